// Round 1
// baseline (412.701 us; speedup 1.0000x reference)
//
#include <hip/hip_runtime.h>

// Problem constants: B=8, C=512, L=4096, Ci=256, K=L/2=2048
#define BATCH 8
#define CIN   512
#define LEN   4096
#define CI    256
#define KLEN  2048

typedef _Float16 half_t;
typedef _Float16 half2_t __attribute__((ext_vector_type(2)));
typedef _Float16 half4_t __attribute__((ext_vector_type(4)));
typedef _Float16 half8_t __attribute__((ext_vector_type(8)));
typedef float    floatx4 __attribute__((ext_vector_type(4)));

// async global->LDS 16B copy (wave-uniform LDS base + lane*16 pattern required)
__device__ __forceinline__ void async16(void* lds_dst, const void* g_src) {
    __builtin_amdgcn_global_load_lds(
        (const __attribute__((address_space(1))) unsigned int*)g_src,
        (__attribute__((address_space(3))) unsigned int*)lds_dst,
        16, 0, 0);
}

// ---------------------------------------------------------------------------
// Kernel A: convert+transpose x[b][c][l] f32 -> xhT[b][l][c] f16.
// 64x64 tiles through LDS. Grid (L/64, CIN/64, B).
// ---------------------------------------------------------------------------
__global__ __launch_bounds__(256) void xpose_kernel(
    const float* __restrict__ x, half_t* __restrict__ xhT)
{
    __shared__ half_t tile[64][72];   // [l][c], 144B rows (16B-aligned)
    const int b = blockIdx.z, c0 = blockIdx.y * 64, l0 = blockIdx.x * 64;
    const int t = threadIdx.x;
    #pragma unroll
    for (int i = 0; i < 4; i++) {
        int fid = t + 256 * i;                 // 1024 float4 reads
        int c = fid >> 4, lb = (fid & 15) << 2;
        float4 v = *(const float4*)(x + ((size_t)b * CIN + c0 + c) * LEN + l0 + lb);
        tile[lb + 0][c] = (half_t)v.x;
        tile[lb + 1][c] = (half_t)v.y;
        tile[lb + 2][c] = (half_t)v.z;
        tile[lb + 3][c] = (half_t)v.w;
    }
    __syncthreads();
    #pragma unroll
    for (int i = 0; i < 2; i++) {
        int fid = t + 256 * i;                 // 512 half8 writes
        int l = fid >> 3, cb = (fid & 7) << 3;
        half8_t v = *(const half8_t*)&tile[l][cb];
        *(half8_t*)(xhT + ((size_t)b * LEN + l0 + l) * CIN + c0 + cb) = v;
    }
}

// ---------------------------------------------------------------------------
// Kernel B: convert weights to fp16. Wh[768][512] = {theta,phi,g} stacked,
// wzh[512][256]. Grid 256x256, 8 elements/thread.
// ---------------------------------------------------------------------------
__global__ __launch_bounds__(256) void wconv_kernel(
    const float* __restrict__ tw, const float* __restrict__ pw,
    const float* __restrict__ gw, const float* __restrict__ wzw,
    half_t* __restrict__ Wh, half_t* __restrict__ wzh)
{
    size_t base = ((size_t)blockIdx.x * 256 + threadIdx.x) * 8;
    const float* src;
    half_t* dst;
    if (base < 768 * 512) {
        size_t o = base >> 9, c = base & 511;
        src = (o < 256 ? tw + o * 512
                       : (o < 512 ? pw + (o - 256) * 512 : gw + (o - 512) * 512)) + c;
        dst = Wh + base;
    } else {
        size_t off = base - 768 * 512;
        src = wzw + off;
        dst = wzh + off;
    }
    float4 a = *(const float4*)src, b2 = *(const float4*)(src + 4);
    half8_t h = { (half_t)a.x, (half_t)a.y, (half_t)a.z, (half_t)a.w,
                  (half_t)b2.x, (half_t)b2.y, (half_t)b2.z, (half_t)b2.w };
    *(half8_t*)dst = h;
}

// ---------------------------------------------------------------------------
// Kernel 1: MFMA projection GEMM.  out[o,l] = sum_c Wh[o,c] xhT[l,c], o=0..767
// covers theta(0-255), phi(256-511), g(512-767); maxpool fused for phi/g.
// 128x128 tile, 4 waves (64x64 each, 4x4 16x16x32 subtiles), BK=32.
// C-layout: col=l (ln), row=o (quad*4+reg). Grid (L/128, 6, B).
// ---------------------------------------------------------------------------
__global__ __launch_bounds__(256, 2) void projmm_kernel(
    const half_t* __restrict__ xhT, const half_t* __restrict__ Wh,
    const float* __restrict__ tb, const float* __restrict__ pb,
    const float* __restrict__ gb,
    half_t* __restrict__ thetaT, half_t* __restrict__ phiT,
    half_t* __restrict__ gH)
{
    __shared__ half_t wsm[128 * 32];   // W tile [o][c], 64B rows
    __shared__ half_t xsm[128 * 32];   // x tile [l][c], 64B rows

    const int b  = blockIdx.z;
    const int o0 = blockIdx.y * 128;
    const int l0 = blockIdx.x * 128;
    const int t  = threadIdx.x;
    const int lane = t & 63, w = t >> 6;
    const int ln = lane & 15, quad = lane >> 4;
    const int wm = w >> 1, wn = w & 1;

    floatx4 acc[4][4];
    #pragma unroll
    for (int mi = 0; mi < 4; mi++)
        #pragma unroll
        for (int nj = 0; nj < 4; nj++) acc[mi][nj] = (floatx4)(0.0f);

    const half_t* Wb = Wh + (size_t)o0 * 512;
    const half_t* xb = xhT + ((size_t)b * LEN + l0) * CIN;

    for (int k0 = 0; k0 < 512; k0 += 32) {
        __syncthreads();
        #pragma unroll
        for (int it = 0; it < 2; it++) {
            int off = t * 16 + it * 4096;       // LDS byte offset
            int row = off >> 6, c8 = (off >> 4) & 3;
            async16(&wsm[off >> 1], Wb + (size_t)row * 512 + k0 + c8 * 8);
            async16(&xsm[off >> 1], xb + (size_t)row * CIN + k0 + c8 * 8);
        }
        __syncthreads();
        half8_t af[4], bf[4];
        #pragma unroll
        for (int mi = 0; mi < 4; mi++)
            af[mi] = *(const half8_t*)&wsm[(wm * 64 + mi * 16 + ln) * 32 + quad * 8];
        #pragma unroll
        for (int nj = 0; nj < 4; nj++)
            bf[nj] = *(const half8_t*)&xsm[(wn * 64 + nj * 16 + ln) * 32 + quad * 8];
        #pragma unroll
        for (int mi = 0; mi < 4; mi++)
            #pragma unroll
            for (int nj = 0; nj < 4; nj++)
                acc[mi][nj] = __builtin_amdgcn_mfma_f32_16x16x32_f16(
                                  af[mi], bf[nj], acc[mi][nj], 0, 0, 0);
    }

    const int which = o0 >> 8;          // 0=theta, 1=phi, 2=g
    const int obase = o0 & 255;
    const float* Bp = which == 0 ? tb : (which == 1 ? pb : gb);

    float bias[4][4];
    #pragma unroll
    for (int mi = 0; mi < 4; mi++)
        #pragma unroll
        for (int r = 0; r < 4; r++)
            bias[mi][r] = Bp[obase + wm * 64 + mi * 16 + quad * 4 + r];

    if (which == 0) {
        #pragma unroll
        for (int mi = 0; mi < 4; mi++) {
            int o = obase + wm * 64 + mi * 16 + quad * 4;
            #pragma unroll
            for (int nj = 0; nj < 4; nj++) {
                int l = l0 + wn * 64 + nj * 16 + ln;
                half4_t v = { (half_t)(acc[mi][nj][0] + bias[mi][0]),
                              (half_t)(acc[mi][nj][1] + bias[mi][1]),
                              (half_t)(acc[mi][nj][2] + bias[mi][2]),
                              (half_t)(acc[mi][nj][3] + bias[mi][3]) };
                *(half4_t*)(thetaT + ((size_t)b * LEN + l) * CI + o) = v;
            }
        }
    } else {
        #pragma unroll
        for (int mi = 0; mi < 4; mi++) {
            int o = obase + wm * 64 + mi * 16 + quad * 4;
            #pragma unroll
            for (int nj = 0; nj < 4; nj++) {
                int l = l0 + wn * 64 + nj * 16 + ln;
                float mx[4];
                #pragma unroll
                for (int r = 0; r < 4; r++) {
                    float other = __shfl_xor(acc[mi][nj][r], 1);
                    mx[r] = fmaxf(acc[mi][nj][r], other) + bias[mi][r];
                }
                if ((ln & 1) == 0) {
                    int kk = l >> 1;
                    if (which == 1) {
                        half4_t v = { (half_t)mx[0], (half_t)mx[1],
                                      (half_t)mx[2], (half_t)mx[3] };
                        *(half4_t*)(phiT + ((size_t)b * KLEN + kk) * CI + o) = v;
                    } else {
                        #pragma unroll
                        for (int r = 0; r < 4; r++)
                            gH[((size_t)b * CI + o + r) * KLEN + kk] = (half_t)mx[r];
                    }
                }
            }
        }
    }
}

// ---------------------------------------------------------------------------
// Kernel 2: MFMA flash attention. Each wave now owns TWO 16-q blocks (32 q)
// so every phi_s/g_s LDS fragment read feeds 2 MFMAs: per-FLOP LDS read
// traffic halves (LDS pipe was ~65% busy + 22% bank-conflict cycles).
// Block covers 128 q. Grid (B, L/128).
// ---------------------------------------------------------------------------
__global__ __launch_bounds__(256, 2) void attn_kernel(
    const half_t* __restrict__ thetaT,   // [B][L][CI]
    const half_t* __restrict__ phiT,     // [B][KLEN][CI]
    const half_t* __restrict__ gH,       // [B][CI][KLEN]
    half_t* __restrict__ yhT)            // [B][LEN][CI]
{
    __shared__ half_t phi_s[64 * 256];   // 64 rows x 512B, granule-swizzled
    __shared__ half_t g_s[256 * 64];     // 256 rows x 128B, granule-swizzled

    const int b    = blockIdx.x;
    const int q0   = blockIdx.y * 128;
    const int t    = threadIdx.x;
    const int w    = t >> 6;
    const int lane = t & 63;
    const int ln   = lane & 15;
    const int quad = lane >> 4;
    const int qw   = q0 + w * 32;        // wave's 32-q base

    half8_t thf[2][8];
    #pragma unroll
    for (int u = 0; u < 2; u++) {
        const half_t* thb = thetaT + ((size_t)b * LEN + qw + u * 16 + ln) * CI + quad * 8;
        #pragma unroll
        for (int ch = 0; ch < 8; ch++)
            thf[u][ch] = *(const half8_t*)(thb + ch * 32);
    }

    floatx4 O[2][16];
    #pragma unroll
    for (int u = 0; u < 2; u++)
        #pragma unroll
        for (int i = 0; i < 16; i++) O[u][i] = (floatx4)(0.0f);
    float m_run[2] = { -3.0e38f, -3.0e38f };
    float l_run[2] = { 0.0f, 0.0f };

    const half_t* phib = phiT + (size_t)b * KLEN * CI;
    const half_t* gb   = gH   + (size_t)b * CI * KLEN;

    for (int kt = 0; kt < KLEN; kt += 64) {
        __syncthreads();
        #pragma unroll
        for (int it = 0; it < 8; it++) {
            int o   = t * 16 + it * 4096;
            int row = o >> 9;
            int gsw = (o >> 4) & 31;
            int gsrc = gsw ^ (row & 31);
            async16(&phi_s[o >> 1],
                    phib + (size_t)(kt + row) * CI + gsrc * 8);
        }
        #pragma unroll
        for (int it = 0; it < 8; it++) {
            int o   = t * 16 + it * 4096;
            int row = o >> 7;
            int gsw = (o >> 4) & 7;
            int gsrc = gsw ^ (row & 7);
            async16(&g_s[o >> 1],
                    gb + (size_t)row * KLEN + kt + gsrc * 8);
        }
        __syncthreads();

        floatx4 S[2][4];
        #pragma unroll
        for (int u = 0; u < 2; u++)
            #pragma unroll
            for (int k16 = 0; k16 < 4; k16++) S[u][k16] = (floatx4)(0.0f);
        #pragma unroll
        for (int k16 = 0; k16 < 4; k16++) {
            int row = k16 * 16 + ln;
            int rs  = row & 31;
            #pragma unroll
            for (int ch = 0; ch < 8; ch++) {
                int gr = (ch * 4 + quad) ^ rs;
                half8_t a = *(const half8_t*)&phi_s[(row << 8) + gr * 8];
                S[0][k16] = __builtin_amdgcn_mfma_f32_16x16x32_f16(
                                a, thf[0][ch], S[0][k16], 0, 0, 0);
                S[1][k16] = __builtin_amdgcn_mfma_f32_16x16x32_f16(
                                a, thf[1][ch], S[1][k16], 0, 0, 0);
            }
        }

        half4_t P[2][4];
        #pragma unroll
        for (int u = 0; u < 2; u++) {
            float tmax = S[u][0][0];
            #pragma unroll
            for (int k16 = 0; k16 < 4; k16++)
                #pragma unroll
                for (int r = 0; r < 4; r++) tmax = fmaxf(tmax, S[u][k16][r]);
            tmax = fmaxf(tmax, __shfl_xor(tmax, 16));
            tmax = fmaxf(tmax, __shfl_xor(tmax, 32));
            float m_new = fmaxf(m_run[u], tmax);
            float alpha = __expf(m_run[u] - m_new);
            m_run[u] = m_new;
            l_run[u] *= alpha;

            #pragma unroll
            for (int k16 = 0; k16 < 4; k16++) {
                float p0 = __expf(S[u][k16][0] - m_new);
                float p1 = __expf(S[u][k16][1] - m_new);
                float p2 = __expf(S[u][k16][2] - m_new);
                float p3 = __expf(S[u][k16][3] - m_new);
                l_run[u] += (p0 + p1) + (p2 + p3);
                half4_t pv = { (half_t)p0, (half_t)p1, (half_t)p2, (half_t)p3 };
                P[u][k16] = pv;
            }
            #pragma unroll
            for (int i = 0; i < 16; i++) O[u][i] *= alpha;
        }

        const int lnm = ln & 7;
        #pragma unroll
        for (int k16 = 0; k16 < 4; k16++) {
            int gr   = (2 * k16 + (quad >> 1)) ^ lnm;
            int coff = gr * 8 + (quad & 1) * 4;
            #pragma unroll
            for (int csub = 0; csub < 16; csub++) {
                int row = csub * 16 + ln;
                half4_t a = *(const half4_t*)&g_s[(row << 6) + coff];
                O[0][csub] = __builtin_amdgcn_mfma_f32_16x16x16f16(
                                 a, P[0][k16], O[0][csub], 0, 0, 0);
                O[1][csub] = __builtin_amdgcn_mfma_f32_16x16x16f16(
                                 a, P[1][k16], O[1][csub], 0, 0, 0);
            }
        }
    }

    #pragma unroll
    for (int u = 0; u < 2; u++) {
        float lr = l_run[u];
        lr += __shfl_xor(lr, 16);
        lr += __shfl_xor(lr, 32);
        float inv = 1.0f / lr;
        // write yhT[b][q][c]: per lane fixed q=qw+u*16+ln, 16 x half4
        half_t* yb = yhT + ((size_t)b * LEN + qw + u * 16 + ln) * CI;
        #pragma unroll
        for (int csub = 0; csub < 16; csub++) {
            int c = csub * 16 + quad * 4;
            half4_t v = { (half_t)(O[u][csub][0] * inv), (half_t)(O[u][csub][1] * inv),
                          (half_t)(O[u][csub][2] * inv), (half_t)(O[u][csub][3] * inv) };
            *(half4_t*)(yb + c) = v;
        }
    }
}

// ---------------------------------------------------------------------------
// Kernel 3: MFMA zgemm. z[o,l] = sum_c wzh[o,c] yhT[l,c] + wz_b, into d_out,
// plus BN partial sums. Orientation m=l, n=o -> float4 stores along l.
// Grid (L/128, 4, B).
// ---------------------------------------------------------------------------
__global__ __launch_bounds__(256, 2) void zmm_kernel(
    const half_t* __restrict__ yhT, const half_t* __restrict__ wzh,
    const float* __restrict__ wzb, float* __restrict__ z,
    float* __restrict__ bns, float* __restrict__ bnq)
{
    __shared__ half_t ysm[128 * 32];   // y tile [l][c]
    __shared__ half_t wsm[128 * 32];   // W tile [o][c]

    const int b  = blockIdx.z;
    const int o0 = blockIdx.y * 128;
    const int l0 = blockIdx.x * 128;
    const int t  = threadIdx.x;
    const int lane = t & 63, w = t >> 6;
    const int ln = lane & 15, quad = lane >> 4;
    const int wm = w >> 1, wn = w & 1;

    floatx4 acc[4][4];
    #pragma unroll
    for (int mi = 0; mi < 4; mi++)
        #pragma unroll
        for (int nj = 0; nj < 4; nj++) acc[mi][nj] = (floatx4)(0.0f);

    const half_t* yb = yhT + ((size_t)b * LEN + l0) * CI;
    const half_t* Wb = wzh + (size_t)o0 * CI;

    for (int k0 = 0; k0 < 256; k0 += 32) {
        __syncthreads();
        #pragma unroll
        for (int it = 0; it < 2; it++) {
            int off = t * 16 + it * 4096;
            int row = off >> 6, c8 = (off >> 4) & 3;
            async16(&ysm[off >> 1], yb + (size_t)row * CI + k0 + c8 * 8);
            async16(&wsm[off >> 1], Wb + (size_t)row * CI + k0 + c8 * 8);
        }
        __syncthreads();
        half8_t af[4], bf[4];
        #pragma unroll
        for (int mi = 0; mi < 4; mi++)
            af[mi] = *(const half8_t*)&ysm[(wm * 64 + mi * 16 + ln) * 32 + quad * 8];
        #pragma unroll
        for (int nj = 0; nj < 4; nj++)
            bf[nj] = *(const half8_t*)&wsm[(wn * 64 + nj * 16 + ln) * 32 + quad * 8];
        #pragma unroll
        for (int mi = 0; mi < 4; mi++)
            #pragma unroll
            for (int nj = 0; nj < 4; nj++)
                acc[mi][nj] = __builtin_amdgcn_mfma_f32_16x16x32_f16(
                                  af[mi], bf[nj], acc[mi][nj], 0, 0, 0);
    }

    // C: row = l = quad*4+r, col = o = ln
    float s[4] = {0, 0, 0, 0}, s2[4] = {0, 0, 0, 0};
    #pragma unroll
    for (int nj = 0; nj < 4; nj++) {
        int o = o0 + wn * 64 + nj * 16 + ln;
        float bo = wzb[o];
        #pragma unroll
        for (int mi = 0; mi < 4; mi++) {
            int l = l0 + wm * 64 + mi * 16 + quad * 4;
            float4 v = make_float4(acc[mi][nj][0] + bo, acc[mi][nj][1] + bo,
                                   acc[mi][nj][2] + bo, acc[mi][nj][3] + bo);
            *(float4*)(z + ((size_t)b * CIN + o) * LEN + l) = v;
            s[nj]  += (v.x + v.y) + (v.z + v.w);
            s2[nj] += (v.x * v.x + v.y * v.y) + (v.z * v.z + v.w * v.w);
        }
    }
    #pragma unroll
    for (int nj = 0; nj < 4; nj++) {
        float sv = s[nj], qv = s2[nj];
        sv += __shfl_xor(sv, 16); sv += __shfl_xor(sv, 32);
        qv += __shfl_xor(qv, 16); qv += __shfl_xor(qv, 32);
        if (quad == 0) {
            int o = o0 + wn * 64 + nj * 16 + ln;
            atomicAdd(&bns[o], sv);
            atomicAdd(&bnq[o], qv);
        }
    }
}

// ---------------------------------------------------------------------------
// Kernel 4: BN normalize (batch stats, biased var) + residual, in-place.
// ---------------------------------------------------------------------------
__global__ __launch_bounds__(256) void bn_kernel(
    float* __restrict__ z, const float* __restrict__ x,
    const float* __restrict__ bns, const float* __restrict__ bnq,
    const float* __restrict__ gamma, const float* __restrict__ beta)
{
    size_t i4 = (size_t)blockIdx.x * 256 + threadIdx.x;
    size_t base = i4 << 2;
    int c = (int)((base >> 12) & (CIN - 1));
    const float invn = 1.0f / (BATCH * LEN);
    float mean = bns[c] * invn;
    float var  = bnq[c] * invn - mean * mean;
    float sc = gamma[c] * rsqrtf(var + 1e-5f);
    float sh = beta[c] - mean * sc;
    float4 zv = *(const float4*)(z + base);
    float4 xv = *(const float4*)(x + base);
    float4 o;
    o.x = zv.x * sc + sh + xv.x;
    o.y = zv.y * sc + sh + xv.y;
    o.z = zv.z * sc + sh + xv.z;
    o.w = zv.w * sc + sh + xv.w;
    *(float4*)(z + base) = o;
}

// ---------------------------------------------------------------------------
extern "C" void kernel_launch(void* const* d_in, const int* in_sizes, int n_in,
                              void* d_out, int out_size, void* d_ws, size_t ws_size,
                              hipStream_t stream)
{
    const float* x     = (const float*)d_in[0];
    const float* tw    = (const float*)d_in[1];
    const float* tb    = (const float*)d_in[2];
    const float* pw    = (const float*)d_in[3];
    const float* pb    = (const float*)d_in[4];
    const float* gw    = (const float*)d_in[5];
    const float* gb    = (const float*)d_in[6];
    const float* wzw   = (const float*)d_in[7];
    const float* wzb   = (const float*)d_in[8];
    const float* gamma = (const float*)d_in[9];
    const float* beta  = (const float*)d_in[10];

    float* out = (float*)d_out;

    half_t* xhT    = (half_t*)d_ws;                              // 33.6 MB
    half_t* thetaT = xhT    + (size_t)BATCH * LEN * CIN;         // 16.8 MB
    half_t* phiT   = thetaT + (size_t)BATCH * LEN * CI;          //  8.4 MB
    half_t* gH     = phiT   + (size_t)BATCH * KLEN * CI;         //  8.4 MB
    half_t* yhT    = gH     + (size_t)BATCH * CI * KLEN;         // 16.8 MB
    half_t* Wh     = yhT    + (size_t)BATCH * LEN * CI;          // 768 KB
    half_t* wzh    = Wh     + (size_t)768 * 512;                 // 256 KB
    float*  bns    = (float*)(wzh + (size_t)512 * 256);
    float*  bnq    = bns + CIN;

    hipMemsetAsync(bns, 0, 2 * CIN * sizeof(float), stream);

    wconv_kernel<<<256, 256, 0, stream>>>(tw, pw, gw, wzw, Wh, wzh);

    xpose_kernel<<<dim3(LEN / 64, CIN / 64, BATCH), 256, 0, stream>>>(x, xhT);

    projmm_kernel<<<dim3(LEN / 128, 6, BATCH), 256, 0, stream>>>(
        xhT, Wh, tb, pb, gb, thetaT, phiT, gH);

    attn_kernel<<<dim3(BATCH, LEN / 128), 256, 0, stream>>>(
        thetaT, phiT, gH, yhT);

    zmm_kernel<<<dim3(LEN / 128, CIN / 128, BATCH), 256, 0, stream>>>(
        yhT, wzh, wzb, out, bns, bnq);

    bn_kernel<<<(BATCH * CIN * LEN) / 4 / 256, 256, 0, stream>>>(
        out, x, bns, bnq, gamma, beta);
}

// Round 2
// 378.736 us; speedup vs baseline: 1.0897x; 1.0897x over previous
//
#include <hip/hip_runtime.h>

// Problem constants: B=8, C=512, L=4096, Ci=256, K=L/2=2048
#define BATCH 8
#define CIN   512
#define LEN   4096
#define CI    256
#define KLEN  2048

typedef _Float16 half_t;
typedef _Float16 half2_t __attribute__((ext_vector_type(2)));
typedef _Float16 half4_t __attribute__((ext_vector_type(4)));
typedef _Float16 half8_t __attribute__((ext_vector_type(8)));
typedef float    floatx4 __attribute__((ext_vector_type(4)));

// async global->LDS 16B copy (wave-uniform LDS base + lane*16 pattern required)
__device__ __forceinline__ void async16(void* lds_dst, const void* g_src) {
    __builtin_amdgcn_global_load_lds(
        (const __attribute__((address_space(1))) unsigned int*)g_src,
        (__attribute__((address_space(3))) unsigned int*)lds_dst,
        16, 0, 0);
}

// ---------------------------------------------------------------------------
// Kernel A: convert+transpose x[b][c][l] f32 -> xhT[b][l][c] f16.
// 64x64 tiles through LDS. Grid (L/64, CIN/64, B).
// ---------------------------------------------------------------------------
__global__ __launch_bounds__(256) void xpose_kernel(
    const float* __restrict__ x, half_t* __restrict__ xhT)
{
    __shared__ half_t tile[64][72];   // [l][c], 144B rows (16B-aligned)
    const int b = blockIdx.z, c0 = blockIdx.y * 64, l0 = blockIdx.x * 64;
    const int t = threadIdx.x;
    #pragma unroll
    for (int i = 0; i < 4; i++) {
        int fid = t + 256 * i;                 // 1024 float4 reads
        int c = fid >> 4, lb = (fid & 15) << 2;
        float4 v = *(const float4*)(x + ((size_t)b * CIN + c0 + c) * LEN + l0 + lb);
        tile[lb + 0][c] = (half_t)v.x;
        tile[lb + 1][c] = (half_t)v.y;
        tile[lb + 2][c] = (half_t)v.z;
        tile[lb + 3][c] = (half_t)v.w;
    }
    __syncthreads();
    #pragma unroll
    for (int i = 0; i < 2; i++) {
        int fid = t + 256 * i;                 // 512 half8 writes
        int l = fid >> 3, cb = (fid & 7) << 3;
        half8_t v = *(const half8_t*)&tile[l][cb];
        *(half8_t*)(xhT + ((size_t)b * LEN + l0 + l) * CIN + c0 + cb) = v;
    }
}

// ---------------------------------------------------------------------------
// Kernel B: convert weights to fp16. Wh[768][512] = {theta,phi,g} stacked,
// wzh[512][256]. Grid 256x256, 8 elements/thread.
// ---------------------------------------------------------------------------
__global__ __launch_bounds__(256) void wconv_kernel(
    const float* __restrict__ tw, const float* __restrict__ pw,
    const float* __restrict__ gw, const float* __restrict__ wzw,
    half_t* __restrict__ Wh, half_t* __restrict__ wzh)
{
    size_t base = ((size_t)blockIdx.x * 256 + threadIdx.x) * 8;
    const float* src;
    half_t* dst;
    if (base < 768 * 512) {
        size_t o = base >> 9, c = base & 511;
        src = (o < 256 ? tw + o * 512
                       : (o < 512 ? pw + (o - 256) * 512 : gw + (o - 512) * 512)) + c;
        dst = Wh + base;
    } else {
        size_t off = base - 768 * 512;
        src = wzw + off;
        dst = wzh + off;
    }
    float4 a = *(const float4*)src, b2 = *(const float4*)(src + 4);
    half8_t h = { (half_t)a.x, (half_t)a.y, (half_t)a.z, (half_t)a.w,
                  (half_t)b2.x, (half_t)b2.y, (half_t)b2.z, (half_t)b2.w };
    *(half8_t*)dst = h;
}

// ---------------------------------------------------------------------------
// Kernel 1: MFMA projection GEMM.  out[o,l] = sum_c Wh[o,c] xhT[l,c], o=0..767
// covers theta(0-255), phi(256-511), g(512-767); maxpool fused for phi/g.
// 128x128 tile, 4 waves (64x64 each, 4x4 16x16x32 subtiles), BK=32.
// C-layout: col=l (ln), row=o (quad*4+reg). Grid (L/128, 6, B).
// ---------------------------------------------------------------------------
__global__ __launch_bounds__(256, 2) void projmm_kernel(
    const half_t* __restrict__ xhT, const half_t* __restrict__ Wh,
    const float* __restrict__ tb, const float* __restrict__ pb,
    const float* __restrict__ gb,
    half_t* __restrict__ thetaT, half_t* __restrict__ phiT,
    half_t* __restrict__ gH)
{
    __shared__ half_t wsm[128 * 32];   // W tile [o][c], 64B rows
    __shared__ half_t xsm[128 * 32];   // x tile [l][c], 64B rows

    const int b  = blockIdx.z;
    const int o0 = blockIdx.y * 128;
    const int l0 = blockIdx.x * 128;
    const int t  = threadIdx.x;
    const int lane = t & 63, w = t >> 6;
    const int ln = lane & 15, quad = lane >> 4;
    const int wm = w >> 1, wn = w & 1;

    floatx4 acc[4][4];
    #pragma unroll
    for (int mi = 0; mi < 4; mi++)
        #pragma unroll
        for (int nj = 0; nj < 4; nj++) acc[mi][nj] = (floatx4)(0.0f);

    const half_t* Wb = Wh + (size_t)o0 * 512;
    const half_t* xb = xhT + ((size_t)b * LEN + l0) * CIN;

    for (int k0 = 0; k0 < 512; k0 += 32) {
        __syncthreads();
        #pragma unroll
        for (int it = 0; it < 2; it++) {
            int off = t * 16 + it * 4096;       // LDS byte offset
            int row = off >> 6, c8 = (off >> 4) & 3;
            async16(&wsm[off >> 1], Wb + (size_t)row * 512 + k0 + c8 * 8);
            async16(&xsm[off >> 1], xb + (size_t)row * CIN + k0 + c8 * 8);
        }
        __syncthreads();
        half8_t af[4], bf[4];
        #pragma unroll
        for (int mi = 0; mi < 4; mi++)
            af[mi] = *(const half8_t*)&wsm[(wm * 64 + mi * 16 + ln) * 32 + quad * 8];
        #pragma unroll
        for (int nj = 0; nj < 4; nj++)
            bf[nj] = *(const half8_t*)&xsm[(wn * 64 + nj * 16 + ln) * 32 + quad * 8];
        #pragma unroll
        for (int mi = 0; mi < 4; mi++)
            #pragma unroll
            for (int nj = 0; nj < 4; nj++)
                acc[mi][nj] = __builtin_amdgcn_mfma_f32_16x16x32_f16(
                                  af[mi], bf[nj], acc[mi][nj], 0, 0, 0);
    }

    const int which = o0 >> 8;          // 0=theta, 1=phi, 2=g
    const int obase = o0 & 255;
    const float* Bp = which == 0 ? tb : (which == 1 ? pb : gb);

    float bias[4][4];
    #pragma unroll
    for (int mi = 0; mi < 4; mi++)
        #pragma unroll
        for (int r = 0; r < 4; r++)
            bias[mi][r] = Bp[obase + wm * 64 + mi * 16 + quad * 4 + r];

    if (which == 0) {
        #pragma unroll
        for (int mi = 0; mi < 4; mi++) {
            int o = obase + wm * 64 + mi * 16 + quad * 4;
            #pragma unroll
            for (int nj = 0; nj < 4; nj++) {
                int l = l0 + wn * 64 + nj * 16 + ln;
                half4_t v = { (half_t)(acc[mi][nj][0] + bias[mi][0]),
                              (half_t)(acc[mi][nj][1] + bias[mi][1]),
                              (half_t)(acc[mi][nj][2] + bias[mi][2]),
                              (half_t)(acc[mi][nj][3] + bias[mi][3]) };
                *(half4_t*)(thetaT + ((size_t)b * LEN + l) * CI + o) = v;
            }
        }
    } else {
        #pragma unroll
        for (int mi = 0; mi < 4; mi++) {
            int o = obase + wm * 64 + mi * 16 + quad * 4;
            #pragma unroll
            for (int nj = 0; nj < 4; nj++) {
                int l = l0 + wn * 64 + nj * 16 + ln;
                float mx[4];
                #pragma unroll
                for (int r = 0; r < 4; r++) {
                    float other = __shfl_xor(acc[mi][nj][r], 1);
                    mx[r] = fmaxf(acc[mi][nj][r], other) + bias[mi][r];
                }
                if ((ln & 1) == 0) {
                    int kk = l >> 1;
                    if (which == 1) {
                        half4_t v = { (half_t)mx[0], (half_t)mx[1],
                                      (half_t)mx[2], (half_t)mx[3] };
                        *(half4_t*)(phiT + ((size_t)b * KLEN + kk) * CI + o) = v;
                    } else {
                        #pragma unroll
                        for (int r = 0; r < 4; r++)
                            gH[((size_t)b * CI + o + r) * KLEN + kk] = (half_t)mx[r];
                    }
                }
            }
        }
    }
}

// ---------------------------------------------------------------------------
// Kernel 2: MFMA flash attention. 32 q per wave (halves per-FLOP LDS reads —
// A-operand fragments feed both 16-q halves). 128 q per block, grid 256 =
// 1 block/CU, so:
//  - __launch_bounds__(256,1): allow ~240 VGPRs (round-1 spilled at 128-cap:
//    WRITE_SIZE doubled from scratch traffic)
//  - double-buffered LDS (128KB) with global_load_lds prefetch of tile kt+1
//    issued before compute on kt: staging hides under compute, one barrier/iter
//  - defer-max (THR=8): skip O-rescale when tile max grows <= 8 (wave-uniform
//    branch; P bounded by e^8, fine in f16)
// ---------------------------------------------------------------------------
__global__ __launch_bounds__(256, 1) void attn_kernel(
    const half_t* __restrict__ thetaT,   // [B][L][CI]
    const half_t* __restrict__ phiT,     // [B][KLEN][CI]
    const half_t* __restrict__ gH,       // [B][CI][KLEN]
    half_t* __restrict__ yhT)            // [B][LEN][CI]
{
    __shared__ half_t phi_s[2][64 * 256];   // 2 x 32KB, granule-swizzled
    __shared__ half_t g_s[2][256 * 64];     // 2 x 32KB, granule-swizzled

    const int b    = blockIdx.x;
    const int q0   = blockIdx.y * 128;
    const int t    = threadIdx.x;
    const int w    = t >> 6;
    const int lane = t & 63;
    const int ln   = lane & 15;
    const int quad = lane >> 4;
    const int qw   = q0 + w * 32;        // wave's 32-q base

    const half_t* phib = phiT + (size_t)b * KLEN * CI;
    const half_t* gb   = gH   + (size_t)b * CI * KLEN;

    // prologue: stage tile 0 into buffer 0
    {
        #pragma unroll
        for (int it = 0; it < 8; it++) {
            int o   = t * 16 + it * 4096;
            int row = o >> 9;
            int gsrc = ((o >> 4) & 31) ^ (row & 31);
            async16(&phi_s[0][o >> 1], phib + (size_t)row * CI + gsrc * 8);
        }
        #pragma unroll
        for (int it = 0; it < 8; it++) {
            int o   = t * 16 + it * 4096;
            int row = o >> 7;
            int gsrc = ((o >> 4) & 7) ^ (row & 7);
            async16(&g_s[0][o >> 1], gb + (size_t)row * KLEN + gsrc * 8);
        }
    }

    half8_t thf[2][8];
    #pragma unroll
    for (int u = 0; u < 2; u++) {
        const half_t* thb = thetaT + ((size_t)b * LEN + qw + u * 16 + ln) * CI + quad * 8;
        #pragma unroll
        for (int ch = 0; ch < 8; ch++)
            thf[u][ch] = *(const half8_t*)(thb + ch * 32);
    }

    floatx4 O[2][16];
    #pragma unroll
    for (int u = 0; u < 2; u++)
        #pragma unroll
        for (int i = 0; i < 16; i++) O[u][i] = (floatx4)(0.0f);
    float m_run[2] = { -3.0e38f, -3.0e38f };
    float l_run[2] = { 0.0f, 0.0f };

    __syncthreads();   // tile 0 staged (syncthreads drains vmcnt)

    for (int kti = 0; kti < KLEN / 64; kti++) {
        const int cur = kti & 1;

        // prefetch tile kti+1 into the other buffer; completes by the
        // end-of-iteration barrier (overlaps all of this tile's compute)
        if (kti + 1 < KLEN / 64) {
            const int kt1 = (kti + 1) * 64;
            #pragma unroll
            for (int it = 0; it < 8; it++) {
                int o   = t * 16 + it * 4096;
                int row = o >> 9;
                int gsrc = ((o >> 4) & 31) ^ (row & 31);
                async16(&phi_s[cur ^ 1][o >> 1],
                        phib + (size_t)(kt1 + row) * CI + gsrc * 8);
            }
            #pragma unroll
            for (int it = 0; it < 8; it++) {
                int o   = t * 16 + it * 4096;
                int row = o >> 7;
                int gsrc = ((o >> 4) & 7) ^ (row & 7);
                async16(&g_s[cur ^ 1][o >> 1],
                        gb + (size_t)row * KLEN + kt1 + gsrc * 8);
            }
        }

        // ---- QK^T: S[u] = phi_tile . theta_u ----
        floatx4 S[2][4];
        #pragma unroll
        for (int u = 0; u < 2; u++)
            #pragma unroll
            for (int k16 = 0; k16 < 4; k16++) S[u][k16] = (floatx4)(0.0f);
        #pragma unroll
        for (int k16 = 0; k16 < 4; k16++) {
            int row = k16 * 16 + ln;
            int rs  = row & 31;
            #pragma unroll
            for (int ch = 0; ch < 8; ch++) {
                int gr = (ch * 4 + quad) ^ rs;
                half8_t a = *(const half8_t*)&phi_s[cur][(row << 8) + gr * 8];
                S[0][k16] = __builtin_amdgcn_mfma_f32_16x16x32_f16(
                                a, thf[0][ch], S[0][k16], 0, 0, 0);
                S[1][k16] = __builtin_amdgcn_mfma_f32_16x16x32_f16(
                                a, thf[1][ch], S[1][k16], 0, 0, 0);
            }
        }

        // ---- online softmax with defer-max ----
        half4_t P[2][4];
        #pragma unroll
        for (int u = 0; u < 2; u++) {
            float tmax = S[u][0][0];
            #pragma unroll
            for (int k16 = 0; k16 < 4; k16++)
                #pragma unroll
                for (int r = 0; r < 4; r++) tmax = fmaxf(tmax, S[u][k16][r]);
            tmax = fmaxf(tmax, __shfl_xor(tmax, 16));
            tmax = fmaxf(tmax, __shfl_xor(tmax, 32));
            if (tmax > m_run[u] + 8.0f) {        // wave-uniform rescale
                float alpha = __expf(m_run[u] - tmax);
                m_run[u] = tmax;
                l_run[u] *= alpha;
                #pragma unroll
                for (int i = 0; i < 16; i++) O[u][i] *= alpha;
            }
            float mr = m_run[u];
            #pragma unroll
            for (int k16 = 0; k16 < 4; k16++) {
                float p0 = __expf(S[u][k16][0] - mr);
                float p1 = __expf(S[u][k16][1] - mr);
                float p2 = __expf(S[u][k16][2] - mr);
                float p3 = __expf(S[u][k16][3] - mr);
                l_run[u] += (p0 + p1) + (p2 + p3);
                half4_t pv = { (half_t)p0, (half_t)p1, (half_t)p2, (half_t)p3 };
                P[u][k16] = pv;
            }
        }

        // ---- PV: one g fragment read feeds both u halves ----
        const int lnm = ln & 7;
        #pragma unroll
        for (int k16 = 0; k16 < 4; k16++) {
            int gr   = (2 * k16 + (quad >> 1)) ^ lnm;
            int coff = gr * 8 + (quad & 1) * 4;
            #pragma unroll
            for (int csub = 0; csub < 16; csub++) {
                int row = csub * 16 + ln;
                half4_t a = *(const half4_t*)&g_s[cur][(row << 6) + coff];
                O[0][csub] = __builtin_amdgcn_mfma_f32_16x16x16f16(
                                 a, P[0][k16], O[0][csub], 0, 0, 0);
                O[1][csub] = __builtin_amdgcn_mfma_f32_16x16x16f16(
                                 a, P[1][k16], O[1][csub], 0, 0, 0);
            }
        }

        __syncthreads();   // prefetch complete + all reads of buf cur done
    }

    #pragma unroll
    for (int u = 0; u < 2; u++) {
        float lr = l_run[u];
        lr += __shfl_xor(lr, 16);
        lr += __shfl_xor(lr, 32);
        float inv = 1.0f / lr;
        // write yhT[b][q][c]: per lane fixed q=qw+u*16+ln, 16 x half4
        half_t* yb = yhT + ((size_t)b * LEN + qw + u * 16 + ln) * CI;
        #pragma unroll
        for (int csub = 0; csub < 16; csub++) {
            int c = csub * 16 + quad * 4;
            half4_t v = { (half_t)(O[u][csub][0] * inv), (half_t)(O[u][csub][1] * inv),
                          (half_t)(O[u][csub][2] * inv), (half_t)(O[u][csub][3] * inv) };
            *(half4_t*)(yb + c) = v;
        }
    }
}

// ---------------------------------------------------------------------------
// Kernel 3: MFMA zgemm. z[o,l] = sum_c wzh[o,c] yhT[l,c] + wz_b, into d_out,
// plus BN partial sums. Orientation m=l, n=o -> float4 stores along l.
// Grid (L/128, 4, B).
// ---------------------------------------------------------------------------
__global__ __launch_bounds__(256, 2) void zmm_kernel(
    const half_t* __restrict__ yhT, const half_t* __restrict__ wzh,
    const float* __restrict__ wzb, float* __restrict__ z,
    float* __restrict__ bns, float* __restrict__ bnq)
{
    __shared__ half_t ysm[128 * 32];   // y tile [l][c]
    __shared__ half_t wsm[128 * 32];   // W tile [o][c]

    const int b  = blockIdx.z;
    const int o0 = blockIdx.y * 128;
    const int l0 = blockIdx.x * 128;
    const int t  = threadIdx.x;
    const int lane = t & 63, w = t >> 6;
    const int ln = lane & 15, quad = lane >> 4;
    const int wm = w >> 1, wn = w & 1;

    floatx4 acc[4][4];
    #pragma unroll
    for (int mi = 0; mi < 4; mi++)
        #pragma unroll
        for (int nj = 0; nj < 4; nj++) acc[mi][nj] = (floatx4)(0.0f);

    const half_t* yb = yhT + ((size_t)b * LEN + l0) * CI;
    const half_t* Wb = wzh + (size_t)o0 * CI;

    for (int k0 = 0; k0 < 256; k0 += 32) {
        __syncthreads();
        #pragma unroll
        for (int it = 0; it < 2; it++) {
            int off = t * 16 + it * 4096;
            int row = off >> 6, c8 = (off >> 4) & 3;
            async16(&ysm[off >> 1], yb + (size_t)row * CI + k0 + c8 * 8);
            async16(&wsm[off >> 1], Wb + (size_t)row * CI + k0 + c8 * 8);
        }
        __syncthreads();
        half8_t af[4], bf[4];
        #pragma unroll
        for (int mi = 0; mi < 4; mi++)
            af[mi] = *(const half8_t*)&ysm[(wm * 64 + mi * 16 + ln) * 32 + quad * 8];
        #pragma unroll
        for (int nj = 0; nj < 4; nj++)
            bf[nj] = *(const half8_t*)&wsm[(wn * 64 + nj * 16 + ln) * 32 + quad * 8];
        #pragma unroll
        for (int mi = 0; mi < 4; mi++)
            #pragma unroll
            for (int nj = 0; nj < 4; nj++)
                acc[mi][nj] = __builtin_amdgcn_mfma_f32_16x16x32_f16(
                                  af[mi], bf[nj], acc[mi][nj], 0, 0, 0);
    }

    // C: row = l = quad*4+r, col = o = ln
    float s[4] = {0, 0, 0, 0}, s2[4] = {0, 0, 0, 0};
    #pragma unroll
    for (int nj = 0; nj < 4; nj++) {
        int o = o0 + wn * 64 + nj * 16 + ln;
        float bo = wzb[o];
        #pragma unroll
        for (int mi = 0; mi < 4; mi++) {
            int l = l0 + wm * 64 + mi * 16 + quad * 4;
            float4 v = make_float4(acc[mi][nj][0] + bo, acc[mi][nj][1] + bo,
                                   acc[mi][nj][2] + bo, acc[mi][nj][3] + bo);
            *(float4*)(z + ((size_t)b * CIN + o) * LEN + l) = v;
            s[nj]  += (v.x + v.y) + (v.z + v.w);
            s2[nj] += (v.x * v.x + v.y * v.y) + (v.z * v.z + v.w * v.w);
        }
    }
    #pragma unroll
    for (int nj = 0; nj < 4; nj++) {
        float sv = s[nj], qv = s2[nj];
        sv += __shfl_xor(sv, 16); sv += __shfl_xor(sv, 32);
        qv += __shfl_xor(qv, 16); qv += __shfl_xor(qv, 32);
        if (quad == 0) {
            int o = o0 + wn * 64 + nj * 16 + ln;
            atomicAdd(&bns[o], sv);
            atomicAdd(&bnq[o], qv);
        }
    }
}

// ---------------------------------------------------------------------------
// Kernel 4: BN normalize (batch stats, biased var) + residual, in-place.
// ---------------------------------------------------------------------------
__global__ __launch_bounds__(256) void bn_kernel(
    float* __restrict__ z, const float* __restrict__ x,
    const float* __restrict__ bns, const float* __restrict__ bnq,
    const float* __restrict__ gamma, const float* __restrict__ beta)
{
    size_t i4 = (size_t)blockIdx.x * 256 + threadIdx.x;
    size_t base = i4 << 2;
    int c = (int)((base >> 12) & (CIN - 1));
    const float invn = 1.0f / (BATCH * LEN);
    float mean = bns[c] * invn;
    float var  = bnq[c] * invn - mean * mean;
    float sc = gamma[c] * rsqrtf(var + 1e-5f);
    float sh = beta[c] - mean * sc;
    float4 zv = *(const float4*)(z + base);
    float4 xv = *(const float4*)(x + base);
    float4 o;
    o.x = zv.x * sc + sh + xv.x;
    o.y = zv.y * sc + sh + xv.y;
    o.z = zv.z * sc + sh + xv.z;
    o.w = zv.w * sc + sh + xv.w;
    *(float4*)(z + base) = o;
}

// ---------------------------------------------------------------------------
extern "C" void kernel_launch(void* const* d_in, const int* in_sizes, int n_in,
                              void* d_out, int out_size, void* d_ws, size_t ws_size,
                              hipStream_t stream)
{
    const float* x     = (const float*)d_in[0];
    const float* tw    = (const float*)d_in[1];
    const float* tb    = (const float*)d_in[2];
    const float* pw    = (const float*)d_in[3];
    const float* pb    = (const float*)d_in[4];
    const float* gw    = (const float*)d_in[5];
    const float* gb    = (const float*)d_in[6];
    const float* wzw   = (const float*)d_in[7];
    const float* wzb   = (const float*)d_in[8];
    const float* gamma = (const float*)d_in[9];
    const float* beta  = (const float*)d_in[10];

    float* out = (float*)d_out;

    half_t* xhT    = (half_t*)d_ws;                              // 33.6 MB
    half_t* thetaT = xhT    + (size_t)BATCH * LEN * CIN;         // 16.8 MB
    half_t* phiT   = thetaT + (size_t)BATCH * LEN * CI;          //  8.4 MB
    half_t* gH     = phiT   + (size_t)BATCH * KLEN * CI;         //  8.4 MB
    half_t* yhT    = gH     + (size_t)BATCH * CI * KLEN;         // 16.8 MB
    half_t* Wh     = yhT    + (size_t)BATCH * LEN * CI;          // 768 KB
    half_t* wzh    = Wh     + (size_t)768 * 512;                 // 256 KB
    float*  bns    = (float*)(wzh + (size_t)512 * 256);
    float*  bnq    = bns + CIN;

    hipMemsetAsync(bns, 0, 2 * CIN * sizeof(float), stream);

    wconv_kernel<<<256, 256, 0, stream>>>(tw, pw, gw, wzw, Wh, wzh);

    xpose_kernel<<<dim3(LEN / 64, CIN / 64, BATCH), 256, 0, stream>>>(x, xhT);

    projmm_kernel<<<dim3(LEN / 128, 6, BATCH), 256, 0, stream>>>(
        xhT, Wh, tb, pb, gb, thetaT, phiT, gH);

    attn_kernel<<<dim3(BATCH, LEN / 128), 256, 0, stream>>>(
        thetaT, phiT, gH, yhT);

    zmm_kernel<<<dim3(LEN / 128, CIN / 128, BATCH), 256, 0, stream>>>(
        yhT, wzh, wzb, out, bns, bnq);

    bn_kernel<<<(BATCH * CIN * LEN) / 4 / 256, 256, 0, stream>>>(
        out, x, bns, bnq, gamma, beta);
}

// Round 3
// 351.078 us; speedup vs baseline: 1.1755x; 1.0788x over previous
//
#include <hip/hip_runtime.h>

// Problem constants: B=8, C=512, L=4096, Ci=256, K=L/2=2048
#define BATCH 8
#define CIN   512
#define LEN   4096
#define CI    256
#define KLEN  2048

typedef _Float16 half_t;
typedef _Float16 half2_t __attribute__((ext_vector_type(2)));
typedef _Float16 half4_t __attribute__((ext_vector_type(4)));
typedef _Float16 half8_t __attribute__((ext_vector_type(8)));
typedef float    floatx4 __attribute__((ext_vector_type(4)));

// async global->LDS 16B copy (wave-uniform LDS base + lane*16 pattern required)
__device__ __forceinline__ void async16(void* lds_dst, const void* g_src) {
    __builtin_amdgcn_global_load_lds(
        (const __attribute__((address_space(1))) unsigned int*)g_src,
        (__attribute__((address_space(3))) unsigned int*)lds_dst,
        16, 0, 0);
}

// ---------------------------------------------------------------------------
// Kernel A: convert+transpose x[b][c][l] f32 -> xhT[b][l][c] f16.
// 64x64 tiles through LDS. Grid (L/64, CIN/64, B).
// ---------------------------------------------------------------------------
__global__ __launch_bounds__(256) void xpose_kernel(
    const float* __restrict__ x, half_t* __restrict__ xhT)
{
    __shared__ half_t tile[64][72];   // [l][c], 144B rows (16B-aligned)
    const int b = blockIdx.z, c0 = blockIdx.y * 64, l0 = blockIdx.x * 64;
    const int t = threadIdx.x;
    #pragma unroll
    for (int i = 0; i < 4; i++) {
        int fid = t + 256 * i;                 // 1024 float4 reads
        int c = fid >> 4, lb = (fid & 15) << 2;
        float4 v = *(const float4*)(x + ((size_t)b * CIN + c0 + c) * LEN + l0 + lb);
        tile[lb + 0][c] = (half_t)v.x;
        tile[lb + 1][c] = (half_t)v.y;
        tile[lb + 2][c] = (half_t)v.z;
        tile[lb + 3][c] = (half_t)v.w;
    }
    __syncthreads();
    #pragma unroll
    for (int i = 0; i < 2; i++) {
        int fid = t + 256 * i;                 // 512 half8 writes
        int l = fid >> 3, cb = (fid & 7) << 3;
        half8_t v = *(const half8_t*)&tile[l][cb];
        *(half8_t*)(xhT + ((size_t)b * LEN + l0 + l) * CIN + c0 + cb) = v;
    }
}

// ---------------------------------------------------------------------------
// Kernel B: convert weights to fp16. Wh[768][512] = {theta,phi,g} stacked,
// wzh[512][256]. Grid 256x256, 8 elements/thread.
// ---------------------------------------------------------------------------
__global__ __launch_bounds__(256) void wconv_kernel(
    const float* __restrict__ tw, const float* __restrict__ pw,
    const float* __restrict__ gw, const float* __restrict__ wzw,
    half_t* __restrict__ Wh, half_t* __restrict__ wzh)
{
    size_t base = ((size_t)blockIdx.x * 256 + threadIdx.x) * 8;
    const float* src;
    half_t* dst;
    if (base < 768 * 512) {
        size_t o = base >> 9, c = base & 511;
        src = (o < 256 ? tw + o * 512
                       : (o < 512 ? pw + (o - 256) * 512 : gw + (o - 512) * 512)) + c;
        dst = Wh + base;
    } else {
        size_t off = base - 768 * 512;
        src = wzw + off;
        dst = wzh + off;
    }
    float4 a = *(const float4*)src, b2 = *(const float4*)(src + 4);
    half8_t h = { (half_t)a.x, (half_t)a.y, (half_t)a.z, (half_t)a.w,
                  (half_t)b2.x, (half_t)b2.y, (half_t)b2.z, (half_t)b2.w };
    *(half8_t*)dst = h;
}

// ---------------------------------------------------------------------------
// Kernel 1: MFMA projection GEMM.  out[o,l] = sum_c Wh[o,c] xhT[l,c], o=0..767
// covers theta(0-255), phi(256-511), g(512-767); maxpool fused for phi/g.
// 128x128 tile, 4 waves (64x64 each, 4x4 16x16x32 subtiles), BK=32.
// C-layout: col=l (ln), row=o (quad*4+reg). Grid (L/128, 6, B).
// ---------------------------------------------------------------------------
__global__ __launch_bounds__(256, 2) void projmm_kernel(
    const half_t* __restrict__ xhT, const half_t* __restrict__ Wh,
    const float* __restrict__ tb, const float* __restrict__ pb,
    const float* __restrict__ gb,
    half_t* __restrict__ thetaT, half_t* __restrict__ phiT,
    half_t* __restrict__ gH)
{
    __shared__ half_t wsm[128 * 32];   // W tile [o][c], 64B rows
    __shared__ half_t xsm[128 * 32];   // x tile [l][c], 64B rows

    const int b  = blockIdx.z;
    const int o0 = blockIdx.y * 128;
    const int l0 = blockIdx.x * 128;
    const int t  = threadIdx.x;
    const int lane = t & 63, w = t >> 6;
    const int ln = lane & 15, quad = lane >> 4;
    const int wm = w >> 1, wn = w & 1;

    floatx4 acc[4][4];
    #pragma unroll
    for (int mi = 0; mi < 4; mi++)
        #pragma unroll
        for (int nj = 0; nj < 4; nj++) acc[mi][nj] = (floatx4)(0.0f);

    const half_t* Wb = Wh + (size_t)o0 * 512;
    const half_t* xb = xhT + ((size_t)b * LEN + l0) * CIN;

    for (int k0 = 0; k0 < 512; k0 += 32) {
        __syncthreads();
        #pragma unroll
        for (int it = 0; it < 2; it++) {
            int off = t * 16 + it * 4096;       // LDS byte offset
            int row = off >> 6, c8 = (off >> 4) & 3;
            async16(&wsm[off >> 1], Wb + (size_t)row * 512 + k0 + c8 * 8);
            async16(&xsm[off >> 1], xb + (size_t)row * CIN + k0 + c8 * 8);
        }
        __syncthreads();
        half8_t af[4], bf[4];
        #pragma unroll
        for (int mi = 0; mi < 4; mi++)
            af[mi] = *(const half8_t*)&wsm[(wm * 64 + mi * 16 + ln) * 32 + quad * 8];
        #pragma unroll
        for (int nj = 0; nj < 4; nj++)
            bf[nj] = *(const half8_t*)&xsm[(wn * 64 + nj * 16 + ln) * 32 + quad * 8];
        #pragma unroll
        for (int mi = 0; mi < 4; mi++)
            #pragma unroll
            for (int nj = 0; nj < 4; nj++)
                acc[mi][nj] = __builtin_amdgcn_mfma_f32_16x16x32_f16(
                                  af[mi], bf[nj], acc[mi][nj], 0, 0, 0);
    }

    const int which = o0 >> 8;          // 0=theta, 1=phi, 2=g
    const int obase = o0 & 255;
    const float* Bp = which == 0 ? tb : (which == 1 ? pb : gb);

    float bias[4][4];
    #pragma unroll
    for (int mi = 0; mi < 4; mi++)
        #pragma unroll
        for (int r = 0; r < 4; r++)
            bias[mi][r] = Bp[obase + wm * 64 + mi * 16 + quad * 4 + r];

    if (which == 0) {
        #pragma unroll
        for (int mi = 0; mi < 4; mi++) {
            int o = obase + wm * 64 + mi * 16 + quad * 4;
            #pragma unroll
            for (int nj = 0; nj < 4; nj++) {
                int l = l0 + wn * 64 + nj * 16 + ln;
                half4_t v = { (half_t)(acc[mi][nj][0] + bias[mi][0]),
                              (half_t)(acc[mi][nj][1] + bias[mi][1]),
                              (half_t)(acc[mi][nj][2] + bias[mi][2]),
                              (half_t)(acc[mi][nj][3] + bias[mi][3]) };
                *(half4_t*)(thetaT + ((size_t)b * LEN + l) * CI + o) = v;
            }
        }
    } else {
        #pragma unroll
        for (int mi = 0; mi < 4; mi++) {
            int o = obase + wm * 64 + mi * 16 + quad * 4;
            #pragma unroll
            for (int nj = 0; nj < 4; nj++) {
                int l = l0 + wn * 64 + nj * 16 + ln;
                float mx[4];
                #pragma unroll
                for (int r = 0; r < 4; r++) {
                    float other = __shfl_xor(acc[mi][nj][r], 1);
                    mx[r] = fmaxf(acc[mi][nj][r], other) + bias[mi][r];
                }
                if ((ln & 1) == 0) {
                    int kk = l >> 1;
                    if (which == 1) {
                        half4_t v = { (half_t)mx[0], (half_t)mx[1],
                                      (half_t)mx[2], (half_t)mx[3] };
                        *(half4_t*)(phiT + ((size_t)b * KLEN + kk) * CI + o) = v;
                    } else {
                        #pragma unroll
                        for (int r = 0; r < 4; r++)
                            gH[((size_t)b * CI + o + r) * KLEN + kk] = (half_t)mx[r];
                    }
                }
            }
        }
    }
}

// ---------------------------------------------------------------------------
// Kernel 2: MFMA flash attention (round-0 structure: 16q/wave, 64q/block,
// grid 512 = 2 blocks/CU, 8 waves/CU). Changes vs round-0:
//  - phi granule swizzle ^((row&7)<<2) instead of ^(row&31): old pattern had
//    4 lanes colliding per granule (quad^quad' == ln^ln' collisions) = 4-way
//    bank conflict on every QK^T read (~57k cy/CU of the measured 65k).
//    New swizzle keeps quad in XOR-untouched low bits; ln/ln+8 broadcast.
//  - defer-max (THR=8): skip the 64-fmul O-rescale unless tile max grows >8
//    (wave-uniform branch; P bounded by e^8, f16-safe; validated round 2).
// ---------------------------------------------------------------------------
__global__ __launch_bounds__(256, 2) void attn_kernel(
    const half_t* __restrict__ thetaT,   // [B][L][CI]
    const half_t* __restrict__ phiT,     // [B][KLEN][CI]
    const half_t* __restrict__ gH,       // [B][CI][KLEN]
    half_t* __restrict__ yhT)            // [B][LEN][CI]
{
    __shared__ half_t phi_s[64 * 256];   // 64 rows x 512B, granule-swizzled
    __shared__ half_t g_s[256 * 64];     // 256 rows x 128B, granule-swizzled

    const int b    = blockIdx.x;
    const int q0   = blockIdx.y * 64;
    const int t    = threadIdx.x;
    const int w    = t >> 6;
    const int lane = t & 63;
    const int ln   = lane & 15;
    const int quad = lane >> 4;
    const int qw   = q0 + w * 16;

    half8_t thf[8];
    {
        const half_t* thb = thetaT + ((size_t)b * LEN + qw + ln) * CI + quad * 8;
        #pragma unroll
        for (int ch = 0; ch < 8; ch++)
            thf[ch] = *(const half8_t*)(thb + ch * 32);
    }

    floatx4 O[16];
    #pragma unroll
    for (int i = 0; i < 16; i++) O[i] = (floatx4)(0.0f);
    float m_run = -3.0e38f;
    float l_run = 0.0f;

    const half_t* phib = phiT + (size_t)b * KLEN * CI;
    const half_t* gb   = gH   + (size_t)b * CI * KLEN;

    for (int kt = 0; kt < KLEN; kt += 64) {
        __syncthreads();
        #pragma unroll
        for (int it = 0; it < 8; it++) {
            int o   = t * 16 + it * 4096;
            int row = o >> 9;
            int gsw = (o >> 4) & 31;
            int gsrc = gsw ^ ((row & 7) << 2);
            async16(&phi_s[o >> 1],
                    phib + (size_t)(kt + row) * CI + gsrc * 8);
        }
        #pragma unroll
        for (int it = 0; it < 8; it++) {
            int o   = t * 16 + it * 4096;
            int row = o >> 7;
            int gsw = (o >> 4) & 7;
            int gsrc = gsw ^ (row & 7);
            async16(&g_s[o >> 1],
                    gb + (size_t)row * KLEN + kt + gsrc * 8);
        }
        __syncthreads();

        floatx4 S[4];
        #pragma unroll
        for (int k16 = 0; k16 < 4; k16++) S[k16] = (floatx4)(0.0f);
        #pragma unroll
        for (int k16 = 0; k16 < 4; k16++) {
            int row = k16 * 16 + ln;
            int rs  = (row & 7) << 2;
            #pragma unroll
            for (int ch = 0; ch < 8; ch++) {
                int gr = (ch * 4 + quad) ^ rs;
                half8_t a = *(const half8_t*)&phi_s[(row << 8) + gr * 8];
                S[k16] = __builtin_amdgcn_mfma_f32_16x16x32_f16(
                             a, thf[ch], S[k16], 0, 0, 0);
            }
        }

        float tmax = S[0][0];
        #pragma unroll
        for (int k16 = 0; k16 < 4; k16++)
            #pragma unroll
            for (int r = 0; r < 4; r++) tmax = fmaxf(tmax, S[k16][r]);
        tmax = fmaxf(tmax, __shfl_xor(tmax, 16));
        tmax = fmaxf(tmax, __shfl_xor(tmax, 32));
        if (tmax > m_run + 8.0f) {           // wave-uniform deferred rescale
            float alpha = __expf(m_run - tmax);
            m_run = tmax;
            l_run *= alpha;
            #pragma unroll
            for (int i = 0; i < 16; i++) O[i] *= alpha;
        }

        half4_t P[4];
        #pragma unroll
        for (int k16 = 0; k16 < 4; k16++) {
            float p0 = __expf(S[k16][0] - m_run);
            float p1 = __expf(S[k16][1] - m_run);
            float p2 = __expf(S[k16][2] - m_run);
            float p3 = __expf(S[k16][3] - m_run);
            l_run += (p0 + p1) + (p2 + p3);
            half4_t pv = { (half_t)p0, (half_t)p1, (half_t)p2, (half_t)p3 };
            P[k16] = pv;
        }

        const int lnm = ln & 7;
        #pragma unroll
        for (int k16 = 0; k16 < 4; k16++) {
            int gr   = (2 * k16 + (quad >> 1)) ^ lnm;
            int coff = gr * 8 + (quad & 1) * 4;
            #pragma unroll
            for (int csub = 0; csub < 16; csub++) {
                int row = csub * 16 + ln;
                half4_t a = *(const half4_t*)&g_s[(row << 6) + coff];
                O[csub] = __builtin_amdgcn_mfma_f32_16x16x16f16(
                              a, P[k16], O[csub], 0, 0, 0);
            }
        }
    }

    l_run += __shfl_xor(l_run, 16);
    l_run += __shfl_xor(l_run, 32);
    float inv = 1.0f / l_run;
    // write yhT[b][q][c]: per lane fixed q=qw+ln, 16 x half4 at c=csub*16+quad*4
    half_t* yb = yhT + ((size_t)b * LEN + qw + ln) * CI;
    #pragma unroll
    for (int csub = 0; csub < 16; csub++) {
        int c = csub * 16 + quad * 4;
        half4_t v = { (half_t)(O[csub][0] * inv), (half_t)(O[csub][1] * inv),
                      (half_t)(O[csub][2] * inv), (half_t)(O[csub][3] * inv) };
        *(half4_t*)(yb + c) = v;
    }
}

// ---------------------------------------------------------------------------
// Kernel 3: MFMA zgemm. z[o,l] = sum_c wzh[o,c] yhT[l,c] + wz_b, into d_out,
// plus BN partial sums. Orientation m=l, n=o -> float4 stores along l.
// Grid (L/128, 4, B).
// ---------------------------------------------------------------------------
__global__ __launch_bounds__(256, 2) void zmm_kernel(
    const half_t* __restrict__ yhT, const half_t* __restrict__ wzh,
    const float* __restrict__ wzb, float* __restrict__ z,
    float* __restrict__ bns, float* __restrict__ bnq)
{
    __shared__ half_t ysm[128 * 32];   // y tile [l][c]
    __shared__ half_t wsm[128 * 32];   // W tile [o][c]

    const int b  = blockIdx.z;
    const int o0 = blockIdx.y * 128;
    const int l0 = blockIdx.x * 128;
    const int t  = threadIdx.x;
    const int lane = t & 63, w = t >> 6;
    const int ln = lane & 15, quad = lane >> 4;
    const int wm = w >> 1, wn = w & 1;

    floatx4 acc[4][4];
    #pragma unroll
    for (int mi = 0; mi < 4; mi++)
        #pragma unroll
        for (int nj = 0; nj < 4; nj++) acc[mi][nj] = (floatx4)(0.0f);

    const half_t* yb = yhT + ((size_t)b * LEN + l0) * CI;
    const half_t* Wb = wzh + (size_t)o0 * CI;

    for (int k0 = 0; k0 < 256; k0 += 32) {
        __syncthreads();
        #pragma unroll
        for (int it = 0; it < 2; it++) {
            int off = t * 16 + it * 4096;
            int row = off >> 6, c8 = (off >> 4) & 3;
            async16(&ysm[off >> 1], yb + (size_t)row * CI + k0 + c8 * 8);
            async16(&wsm[off >> 1], Wb + (size_t)row * CI + k0 + c8 * 8);
        }
        __syncthreads();
        half8_t af[4], bf[4];
        #pragma unroll
        for (int mi = 0; mi < 4; mi++)
            af[mi] = *(const half8_t*)&ysm[(wm * 64 + mi * 16 + ln) * 32 + quad * 8];
        #pragma unroll
        for (int nj = 0; nj < 4; nj++)
            bf[nj] = *(const half8_t*)&wsm[(wn * 64 + nj * 16 + ln) * 32 + quad * 8];
        #pragma unroll
        for (int mi = 0; mi < 4; mi++)
            #pragma unroll
            for (int nj = 0; nj < 4; nj++)
                acc[mi][nj] = __builtin_amdgcn_mfma_f32_16x16x32_f16(
                                  af[mi], bf[nj], acc[mi][nj], 0, 0, 0);
    }

    // C: row = l = quad*4+r, col = o = ln
    float s[4] = {0, 0, 0, 0}, s2[4] = {0, 0, 0, 0};
    #pragma unroll
    for (int nj = 0; nj < 4; nj++) {
        int o = o0 + wn * 64 + nj * 16 + ln;
        float bo = wzb[o];
        #pragma unroll
        for (int mi = 0; mi < 4; mi++) {
            int l = l0 + wm * 64 + mi * 16 + quad * 4;
            float4 v = make_float4(acc[mi][nj][0] + bo, acc[mi][nj][1] + bo,
                                   acc[mi][nj][2] + bo, acc[mi][nj][3] + bo);
            *(float4*)(z + ((size_t)b * CIN + o) * LEN + l) = v;
            s[nj]  += (v.x + v.y) + (v.z + v.w);
            s2[nj] += (v.x * v.x + v.y * v.y) + (v.z * v.z + v.w * v.w);
        }
    }
    #pragma unroll
    for (int nj = 0; nj < 4; nj++) {
        float sv = s[nj], qv = s2[nj];
        sv += __shfl_xor(sv, 16); sv += __shfl_xor(sv, 32);
        qv += __shfl_xor(qv, 16); qv += __shfl_xor(qv, 32);
        if (quad == 0) {
            int o = o0 + wn * 64 + nj * 16 + ln;
            atomicAdd(&bns[o], sv);
            atomicAdd(&bnq[o], qv);
        }
    }
}

// ---------------------------------------------------------------------------
// Kernel 4: BN normalize (batch stats, biased var) + residual, in-place.
// ---------------------------------------------------------------------------
__global__ __launch_bounds__(256) void bn_kernel(
    float* __restrict__ z, const float* __restrict__ x,
    const float* __restrict__ bns, const float* __restrict__ bnq,
    const float* __restrict__ gamma, const float* __restrict__ beta)
{
    size_t i4 = (size_t)blockIdx.x * 256 + threadIdx.x;
    size_t base = i4 << 2;
    int c = (int)((base >> 12) & (CIN - 1));
    const float invn = 1.0f / (BATCH * LEN);
    float mean = bns[c] * invn;
    float var  = bnq[c] * invn - mean * mean;
    float sc = gamma[c] * rsqrtf(var + 1e-5f);
    float sh = beta[c] - mean * sc;
    float4 zv = *(const float4*)(z + base);
    float4 xv = *(const float4*)(x + base);
    float4 o;
    o.x = zv.x * sc + sh + xv.x;
    o.y = zv.y * sc + sh + xv.y;
    o.z = zv.z * sc + sh + xv.z;
    o.w = zv.w * sc + sh + xv.w;
    *(float4*)(z + base) = o;
}

// ---------------------------------------------------------------------------
extern "C" void kernel_launch(void* const* d_in, const int* in_sizes, int n_in,
                              void* d_out, int out_size, void* d_ws, size_t ws_size,
                              hipStream_t stream)
{
    const float* x     = (const float*)d_in[0];
    const float* tw    = (const float*)d_in[1];
    const float* tb    = (const float*)d_in[2];
    const float* pw    = (const float*)d_in[3];
    const float* pb    = (const float*)d_in[4];
    const float* gw    = (const float*)d_in[5];
    const float* gb    = (const float*)d_in[6];
    const float* wzw   = (const float*)d_in[7];
    const float* wzb   = (const float*)d_in[8];
    const float* gamma = (const float*)d_in[9];
    const float* beta  = (const float*)d_in[10];

    float* out = (float*)d_out;

    half_t* xhT    = (half_t*)d_ws;                              // 33.6 MB
    half_t* thetaT = xhT    + (size_t)BATCH * LEN * CIN;         // 16.8 MB
    half_t* phiT   = thetaT + (size_t)BATCH * LEN * CI;          //  8.4 MB
    half_t* gH     = phiT   + (size_t)BATCH * KLEN * CI;         //  8.4 MB
    half_t* yhT    = gH     + (size_t)BATCH * CI * KLEN;         // 16.8 MB
    half_t* Wh     = yhT    + (size_t)BATCH * LEN * CI;          // 768 KB
    half_t* wzh    = Wh     + (size_t)768 * 512;                 // 256 KB
    float*  bns    = (float*)(wzh + (size_t)512 * 256);
    float*  bnq    = bns + CIN;

    hipMemsetAsync(bns, 0, 2 * CIN * sizeof(float), stream);

    wconv_kernel<<<256, 256, 0, stream>>>(tw, pw, gw, wzw, Wh, wzh);

    xpose_kernel<<<dim3(LEN / 64, CIN / 64, BATCH), 256, 0, stream>>>(x, xhT);

    projmm_kernel<<<dim3(LEN / 128, 6, BATCH), 256, 0, stream>>>(
        xhT, Wh, tb, pb, gb, thetaT, phiT, gH);

    attn_kernel<<<dim3(BATCH, LEN / 64), 256, 0, stream>>>(
        thetaT, phiT, gH, yhT);

    zmm_kernel<<<dim3(LEN / 128, CIN / 128, BATCH), 256, 0, stream>>>(
        yhT, wzh, wzb, out, bns, bnq);

    bn_kernel<<<(BATCH * CIN * LEN) / 4 / 256, 256, 0, stream>>>(
        out, x, bns, bnq, gamma, beta);
}

// Round 4
// 312.319 us; speedup vs baseline: 1.3214x; 1.1241x over previous
//
#include <hip/hip_runtime.h>

// Problem constants: B=8, C=512, L=4096, Ci=256, K=L/2=2048
#define BATCH 8
#define CIN   512
#define LEN   4096
#define CI    256
#define KLEN  2048

typedef _Float16 half_t;
typedef _Float16 half2_t __attribute__((ext_vector_type(2)));
typedef _Float16 half4_t __attribute__((ext_vector_type(4)));
typedef _Float16 half8_t __attribute__((ext_vector_type(8)));
typedef float    floatx4 __attribute__((ext_vector_type(4)));

// async global->LDS 16B copy (wave-uniform LDS base + lane*16 pattern required)
__device__ __forceinline__ void async16(void* lds_dst, const void* g_src) {
    __builtin_amdgcn_global_load_lds(
        (const __attribute__((address_space(1))) unsigned int*)g_src,
        (__attribute__((address_space(3))) unsigned int*)lds_dst,
        16, 0, 0);
}

// ---------------------------------------------------------------------------
// Kernel A: convert+transpose x[b][c][l] f32 -> xhT[b][l][c] f16.
// 64x64 tiles through LDS. Grid (L/64, CIN/64, B).
// ---------------------------------------------------------------------------
__global__ __launch_bounds__(256) void xpose_kernel(
    const float* __restrict__ x, half_t* __restrict__ xhT)
{
    __shared__ half_t tile[64][72];   // [l][c], 144B rows (16B-aligned)
    const int b = blockIdx.z, c0 = blockIdx.y * 64, l0 = blockIdx.x * 64;
    const int t = threadIdx.x;
    #pragma unroll
    for (int i = 0; i < 4; i++) {
        int fid = t + 256 * i;                 // 1024 float4 reads
        int c = fid >> 4, lb = (fid & 15) << 2;
        float4 v = *(const float4*)(x + ((size_t)b * CIN + c0 + c) * LEN + l0 + lb);
        tile[lb + 0][c] = (half_t)v.x;
        tile[lb + 1][c] = (half_t)v.y;
        tile[lb + 2][c] = (half_t)v.z;
        tile[lb + 3][c] = (half_t)v.w;
    }
    __syncthreads();
    #pragma unroll
    for (int i = 0; i < 2; i++) {
        int fid = t + 256 * i;                 // 512 half8 writes
        int l = fid >> 3, cb = (fid & 7) << 3;
        half8_t v = *(const half8_t*)&tile[l][cb];
        *(half8_t*)(xhT + ((size_t)b * LEN + l0 + l) * CIN + c0 + cb) = v;
    }
}

// ---------------------------------------------------------------------------
// Kernel B: convert weights to fp16. Wh[768][512] = {theta,phi,g} stacked,
// wzh[512][256]. Grid 256x256, 8 elements/thread.
// ---------------------------------------------------------------------------
__global__ __launch_bounds__(256) void wconv_kernel(
    const float* __restrict__ tw, const float* __restrict__ pw,
    const float* __restrict__ gw, const float* __restrict__ wzw,
    half_t* __restrict__ Wh, half_t* __restrict__ wzh)
{
    size_t base = ((size_t)blockIdx.x * 256 + threadIdx.x) * 8;
    const float* src;
    half_t* dst;
    if (base < 768 * 512) {
        size_t o = base >> 9, c = base & 511;
        src = (o < 256 ? tw + o * 512
                       : (o < 512 ? pw + (o - 256) * 512 : gw + (o - 512) * 512)) + c;
        dst = Wh + base;
    } else {
        size_t off = base - 768 * 512;
        src = wzw + off;
        dst = wzh + off;
    }
    float4 a = *(const float4*)src, b2 = *(const float4*)(src + 4);
    half8_t h = { (half_t)a.x, (half_t)a.y, (half_t)a.z, (half_t)a.w,
                  (half_t)b2.x, (half_t)b2.y, (half_t)b2.z, (half_t)b2.w };
    *(half8_t*)dst = h;
}

// ---------------------------------------------------------------------------
// Kernel 1: MFMA projection GEMM.  out[o,l] = sum_c Wh[o,c] xhT[l,c], o=0..767
// covers theta(0-255), phi(256-511), g(512-767); maxpool fused for phi/g.
// 128x128 tile, 4 waves (64x64 each, 4x4 16x16x32 subtiles), BK=32.
// C-layout: col=l (ln), row=o (quad*4+reg). Grid (L/128, 6, B).
// ---------------------------------------------------------------------------
__global__ __launch_bounds__(256, 2) void projmm_kernel(
    const half_t* __restrict__ xhT, const half_t* __restrict__ Wh,
    const float* __restrict__ tb, const float* __restrict__ pb,
    const float* __restrict__ gb,
    half_t* __restrict__ thetaT, half_t* __restrict__ phiT,
    half_t* __restrict__ gH)
{
    __shared__ half_t wsm[128 * 32];   // W tile [o][c], 64B rows
    __shared__ half_t xsm[128 * 32];   // x tile [l][c], 64B rows

    const int b  = blockIdx.z;
    const int o0 = blockIdx.y * 128;
    const int l0 = blockIdx.x * 128;
    const int t  = threadIdx.x;
    const int lane = t & 63, w = t >> 6;
    const int ln = lane & 15, quad = lane >> 4;
    const int wm = w >> 1, wn = w & 1;

    floatx4 acc[4][4];
    #pragma unroll
    for (int mi = 0; mi < 4; mi++)
        #pragma unroll
        for (int nj = 0; nj < 4; nj++) acc[mi][nj] = (floatx4)(0.0f);

    const half_t* Wb = Wh + (size_t)o0 * 512;
    const half_t* xb = xhT + ((size_t)b * LEN + l0) * CIN;

    for (int k0 = 0; k0 < 512; k0 += 32) {
        __syncthreads();
        #pragma unroll
        for (int it = 0; it < 2; it++) {
            int off = t * 16 + it * 4096;       // LDS byte offset
            int row = off >> 6, c8 = (off >> 4) & 3;
            async16(&wsm[off >> 1], Wb + (size_t)row * 512 + k0 + c8 * 8);
            async16(&xsm[off >> 1], xb + (size_t)row * CIN + k0 + c8 * 8);
        }
        __syncthreads();
        half8_t af[4], bf[4];
        #pragma unroll
        for (int mi = 0; mi < 4; mi++)
            af[mi] = *(const half8_t*)&wsm[(wm * 64 + mi * 16 + ln) * 32 + quad * 8];
        #pragma unroll
        for (int nj = 0; nj < 4; nj++)
            bf[nj] = *(const half8_t*)&xsm[(wn * 64 + nj * 16 + ln) * 32 + quad * 8];
        #pragma unroll
        for (int mi = 0; mi < 4; mi++)
            #pragma unroll
            for (int nj = 0; nj < 4; nj++)
                acc[mi][nj] = __builtin_amdgcn_mfma_f32_16x16x32_f16(
                                  af[mi], bf[nj], acc[mi][nj], 0, 0, 0);
    }

    const int which = o0 >> 8;          // 0=theta, 1=phi, 2=g
    const int obase = o0 & 255;
    const float* Bp = which == 0 ? tb : (which == 1 ? pb : gb);

    float bias[4][4];
    #pragma unroll
    for (int mi = 0; mi < 4; mi++)
        #pragma unroll
        for (int r = 0; r < 4; r++)
            bias[mi][r] = Bp[obase + wm * 64 + mi * 16 + quad * 4 + r];

    if (which == 0) {
        #pragma unroll
        for (int mi = 0; mi < 4; mi++) {
            int o = obase + wm * 64 + mi * 16 + quad * 4;
            #pragma unroll
            for (int nj = 0; nj < 4; nj++) {
                int l = l0 + wn * 64 + nj * 16 + ln;
                half4_t v = { (half_t)(acc[mi][nj][0] + bias[mi][0]),
                              (half_t)(acc[mi][nj][1] + bias[mi][1]),
                              (half_t)(acc[mi][nj][2] + bias[mi][2]),
                              (half_t)(acc[mi][nj][3] + bias[mi][3]) };
                *(half4_t*)(thetaT + ((size_t)b * LEN + l) * CI + o) = v;
            }
        }
    } else {
        #pragma unroll
        for (int mi = 0; mi < 4; mi++) {
            int o = obase + wm * 64 + mi * 16 + quad * 4;
            #pragma unroll
            for (int nj = 0; nj < 4; nj++) {
                int l = l0 + wn * 64 + nj * 16 + ln;
                float mx[4];
                #pragma unroll
                for (int r = 0; r < 4; r++) {
                    float other = __shfl_xor(acc[mi][nj][r], 1);
                    mx[r] = fmaxf(acc[mi][nj][r], other) + bias[mi][r];
                }
                if ((ln & 1) == 0) {
                    int kk = l >> 1;
                    if (which == 1) {
                        half4_t v = { (half_t)mx[0], (half_t)mx[1],
                                      (half_t)mx[2], (half_t)mx[3] };
                        *(half4_t*)(phiT + ((size_t)b * KLEN + kk) * CI + o) = v;
                    } else {
                        #pragma unroll
                        for (int r = 0; r < 4; r++)
                            gH[((size_t)b * CI + o + r) * KLEN + kk] = (half_t)mx[r];
                    }
                }
            }
        }
    }
}

// ---------------------------------------------------------------------------
// Kernel 2: MFMA flash attention (16q/wave, 64q/block, grid 512, 2 blk/CU).
// Round-4 changes (conflict model validated by r0/r3 counter deltas:
// b128 serviced 8 lanes/cy, b64 16 lanes/cy):
//  - phi read swizzle back to ^(row&31) (round-0 form, conflict-free:
//    gr&7 = ((ch*4+quad)^ln)&7 bijective per 8-lane group).
//  - phi STAGING permutes tile rows: LDS row rho holds key
//    key(rho)=32*(k16&1)+8*quad+4*(k16>>1)+r, so that per-lane S registers
//    concat to 16x16x32 B-fragments with zero shuffles (softmax is
//    key-order invariant).
//  - PV switched to mfma_16x16x32: g read becomes one b128/lane at chunk
//    (4kk+quad)^(ln&7) -> conflict-free (was b64 with structural 2-way:
//    the whole 1.68e7-conflict floor). Half the g-read instrs + half the
//    PV MFMA count at same FLOPs.
//  - defer-max kept (measured -4.5pt VALUBusy).
// ---------------------------------------------------------------------------
__global__ __launch_bounds__(256, 2) void attn_kernel(
    const half_t* __restrict__ thetaT,   // [B][L][CI]
    const half_t* __restrict__ phiT,     // [B][KLEN][CI]
    const half_t* __restrict__ gH,       // [B][CI][KLEN]
    half_t* __restrict__ yhT)            // [B][LEN][CI]
{
    __shared__ half_t phi_s[64 * 256];   // 64 rows x 512B, swizzled + row-perm
    __shared__ half_t g_s[256 * 64];     // 256 rows x 128B, granule-swizzled

    const int b    = blockIdx.x;
    const int q0   = blockIdx.y * 64;
    const int t    = threadIdx.x;
    const int w    = t >> 6;
    const int lane = t & 63;
    const int ln   = lane & 15;
    const int quad = lane >> 4;
    const int qw   = q0 + w * 16;

    half8_t thf[8];
    {
        const half_t* thb = thetaT + ((size_t)b * LEN + qw + ln) * CI + quad * 8;
        #pragma unroll
        for (int ch = 0; ch < 8; ch++)
            thf[ch] = *(const half8_t*)(thb + ch * 32);
    }

    floatx4 O[16];
    #pragma unroll
    for (int i = 0; i < 16; i++) O[i] = (floatx4)(0.0f);
    float m_run = -3.0e38f;
    float l_run = 0.0f;

    const half_t* phib = phiT + (size_t)b * KLEN * CI;
    const half_t* gb   = gH   + (size_t)b * CI * KLEN;

    for (int kt = 0; kt < KLEN; kt += 64) {
        __syncthreads();
        #pragma unroll
        for (int it = 0; it < 8; it++) {
            int o   = t * 16 + it * 4096;
            int rho = o >> 9;
            int gsw = (o >> 4) & 31;
            int gsrc = gsw ^ (rho & 31);
            // row permutation: LDS row rho holds key(rho)
            int key = ((rho >> 4) & 1) * 32 + ((rho >> 2) & 3) * 8
                    + ((rho >> 5) & 1) * 4 + (rho & 3);
            async16(&phi_s[o >> 1],
                    phib + (size_t)(kt + key) * CI + gsrc * 8);
        }
        #pragma unroll
        for (int it = 0; it < 8; it++) {
            int o   = t * 16 + it * 4096;
            int row = o >> 7;
            int gsw = (o >> 4) & 7;
            int gsrc = gsw ^ (row & 7);
            async16(&g_s[o >> 1],
                    gb + (size_t)row * KLEN + kt + gsrc * 8);
        }
        __syncthreads();

        floatx4 S[4];
        #pragma unroll
        for (int k16 = 0; k16 < 4; k16++) S[k16] = (floatx4)(0.0f);
        #pragma unroll
        for (int k16 = 0; k16 < 4; k16++) {
            int row = k16 * 16 + ln;
            int rs  = row & 31;
            #pragma unroll
            for (int ch = 0; ch < 8; ch++) {
                int gr = (ch * 4 + quad) ^ rs;
                half8_t a = *(const half8_t*)&phi_s[(row << 8) + gr * 8];
                S[k16] = __builtin_amdgcn_mfma_f32_16x16x32_f16(
                             a, thf[ch], S[k16], 0, 0, 0);
            }
        }

        float tmax = S[0][0];
        #pragma unroll
        for (int k16 = 0; k16 < 4; k16++)
            #pragma unroll
            for (int r = 0; r < 4; r++) tmax = fmaxf(tmax, S[k16][r]);
        tmax = fmaxf(tmax, __shfl_xor(tmax, 16));
        tmax = fmaxf(tmax, __shfl_xor(tmax, 32));
        if (tmax > m_run + 8.0f) {           // wave-uniform deferred rescale
            float alpha = __expf(m_run - tmax);
            m_run = tmax;
            l_run *= alpha;
            #pragma unroll
            for (int i = 0; i < 16; i++) O[i] *= alpha;
        }

        // P2[kk] = B-fragment for 16x16x32 PV: halfs j=0..3 from S[kk],
        // j=4..7 from S[kk+2] (register concat; key(rho) makes this exact:
        // lane holds key = 32*kk + 8*quad + j).
        half8_t P2[2];
        #pragma unroll
        for (int kk = 0; kk < 2; kk++) {
            float ps[8];
            #pragma unroll
            for (int j = 0; j < 8; j++) {
                int k16 = kk + ((j >> 2) << 1);
                ps[j] = __expf(S[k16][j & 3] - m_run);
                l_run += ps[j];
            }
            half8_t pv = { (half_t)ps[0], (half_t)ps[1], (half_t)ps[2], (half_t)ps[3],
                           (half_t)ps[4], (half_t)ps[5], (half_t)ps[6], (half_t)ps[7] };
            P2[kk] = pv;
        }

        // PV: one conflict-free b128 g read per MFMA.
        const int lnm = ln & 7;
        #pragma unroll
        for (int kk = 0; kk < 2; kk++) {
            int gchunk = (4 * kk + quad) ^ lnm;     // 16B-chunk within 128B row
            #pragma unroll
            for (int csub = 0; csub < 16; csub++) {
                int row = csub * 16 + ln;
                half8_t a = *(const half8_t*)&g_s[(row << 6) + gchunk * 8];
                O[csub] = __builtin_amdgcn_mfma_f32_16x16x32_f16(
                              a, P2[kk], O[csub], 0, 0, 0);
            }
        }
    }

    l_run += __shfl_xor(l_run, 16);
    l_run += __shfl_xor(l_run, 32);
    float inv = 1.0f / l_run;
    // write yhT[b][q][c]: per lane fixed q=qw+ln, 16 x half4 at c=csub*16+quad*4
    half_t* yb = yhT + ((size_t)b * LEN + qw + ln) * CI;
    #pragma unroll
    for (int csub = 0; csub < 16; csub++) {
        int c = csub * 16 + quad * 4;
        half4_t v = { (half_t)(O[csub][0] * inv), (half_t)(O[csub][1] * inv),
                      (half_t)(O[csub][2] * inv), (half_t)(O[csub][3] * inv) };
        *(half4_t*)(yb + c) = v;
    }
}

// ---------------------------------------------------------------------------
// Kernel 3: MFMA zgemm. z[o,l] = sum_c wzh[o,c] yhT[l,c] + wz_b, into d_out,
// plus BN partial sums. Orientation m=l, n=o -> float4 stores along l.
// Grid (L/128, 4, B).
// ---------------------------------------------------------------------------
__global__ __launch_bounds__(256, 2) void zmm_kernel(
    const half_t* __restrict__ yhT, const half_t* __restrict__ wzh,
    const float* __restrict__ wzb, float* __restrict__ z,
    float* __restrict__ bns, float* __restrict__ bnq)
{
    __shared__ half_t ysm[128 * 32];   // y tile [l][c]
    __shared__ half_t wsm[128 * 32];   // W tile [o][c]

    const int b  = blockIdx.z;
    const int o0 = blockIdx.y * 128;
    const int l0 = blockIdx.x * 128;
    const int t  = threadIdx.x;
    const int lane = t & 63, w = t >> 6;
    const int ln = lane & 15, quad = lane >> 4;
    const int wm = w >> 1, wn = w & 1;

    floatx4 acc[4][4];
    #pragma unroll
    for (int mi = 0; mi < 4; mi++)
        #pragma unroll
        for (int nj = 0; nj < 4; nj++) acc[mi][nj] = (floatx4)(0.0f);

    const half_t* yb = yhT + ((size_t)b * LEN + l0) * CI;
    const half_t* Wb = wzh + (size_t)o0 * CI;

    for (int k0 = 0; k0 < 256; k0 += 32) {
        __syncthreads();
        #pragma unroll
        for (int it = 0; it < 2; it++) {
            int off = t * 16 + it * 4096;
            int row = off >> 6, c8 = (off >> 4) & 3;
            async16(&ysm[off >> 1], yb + (size_t)row * CI + k0 + c8 * 8);
            async16(&wsm[off >> 1], Wb + (size_t)row * CI + k0 + c8 * 8);
        }
        __syncthreads();
        half8_t af[4], bf[4];
        #pragma unroll
        for (int mi = 0; mi < 4; mi++)
            af[mi] = *(const half8_t*)&ysm[(wm * 64 + mi * 16 + ln) * 32 + quad * 8];
        #pragma unroll
        for (int nj = 0; nj < 4; nj++)
            bf[nj] = *(const half8_t*)&wsm[(wn * 64 + nj * 16 + ln) * 32 + quad * 8];
        #pragma unroll
        for (int mi = 0; mi < 4; mi++)
            #pragma unroll
            for (int nj = 0; nj < 4; nj++)
                acc[mi][nj] = __builtin_amdgcn_mfma_f32_16x16x32_f16(
                                  af[mi], bf[nj], acc[mi][nj], 0, 0, 0);
    }

    // C: row = l = quad*4+r, col = o = ln
    float s[4] = {0, 0, 0, 0}, s2[4] = {0, 0, 0, 0};
    #pragma unroll
    for (int nj = 0; nj < 4; nj++) {
        int o = o0 + wn * 64 + nj * 16 + ln;
        float bo = wzb[o];
        #pragma unroll
        for (int mi = 0; mi < 4; mi++) {
            int l = l0 + wm * 64 + mi * 16 + quad * 4;
            float4 v = make_float4(acc[mi][nj][0] + bo, acc[mi][nj][1] + bo,
                                   acc[mi][nj][2] + bo, acc[mi][nj][3] + bo);
            *(float4*)(z + ((size_t)b * CIN + o) * LEN + l) = v;
            s[nj]  += (v.x + v.y) + (v.z + v.w);
            s2[nj] += (v.x * v.x + v.y * v.y) + (v.z * v.z + v.w * v.w);
        }
    }
    #pragma unroll
    for (int nj = 0; nj < 4; nj++) {
        float sv = s[nj], qv = s2[nj];
        sv += __shfl_xor(sv, 16); sv += __shfl_xor(sv, 32);
        qv += __shfl_xor(qv, 16); qv += __shfl_xor(qv, 32);
        if (quad == 0) {
            int o = o0 + wn * 64 + nj * 16 + ln;
            atomicAdd(&bns[o], sv);
            atomicAdd(&bnq[o], qv);
        }
    }
}

// ---------------------------------------------------------------------------
// Kernel 4: BN normalize (batch stats, biased var) + residual, in-place.
// ---------------------------------------------------------------------------
__global__ __launch_bounds__(256) void bn_kernel(
    float* __restrict__ z, const float* __restrict__ x,
    const float* __restrict__ bns, const float* __restrict__ bnq,
    const float* __restrict__ gamma, const float* __restrict__ beta)
{
    size_t i4 = (size_t)blockIdx.x * 256 + threadIdx.x;
    size_t base = i4 << 2;
    int c = (int)((base >> 12) & (CIN - 1));
    const float invn = 1.0f / (BATCH * LEN);
    float mean = bns[c] * invn;
    float var  = bnq[c] * invn - mean * mean;
    float sc = gamma[c] * rsqrtf(var + 1e-5f);
    float sh = beta[c] - mean * sc;
    float4 zv = *(const float4*)(z + base);
    float4 xv = *(const float4*)(x + base);
    float4 o;
    o.x = zv.x * sc + sh + xv.x;
    o.y = zv.y * sc + sh + xv.y;
    o.z = zv.z * sc + sh + xv.z;
    o.w = zv.w * sc + sh + xv.w;
    *(float4*)(z + base) = o;
}

// ---------------------------------------------------------------------------
extern "C" void kernel_launch(void* const* d_in, const int* in_sizes, int n_in,
                              void* d_out, int out_size, void* d_ws, size_t ws_size,
                              hipStream_t stream)
{
    const float* x     = (const float*)d_in[0];
    const float* tw    = (const float*)d_in[1];
    const float* tb    = (const float*)d_in[2];
    const float* pw    = (const float*)d_in[3];
    const float* pb    = (const float*)d_in[4];
    const float* gw    = (const float*)d_in[5];
    const float* gb    = (const float*)d_in[6];
    const float* wzw   = (const float*)d_in[7];
    const float* wzb   = (const float*)d_in[8];
    const float* gamma = (const float*)d_in[9];
    const float* beta  = (const float*)d_in[10];

    float* out = (float*)d_out;

    half_t* xhT    = (half_t*)d_ws;                              // 33.6 MB
    half_t* thetaT = xhT    + (size_t)BATCH * LEN * CIN;         // 16.8 MB
    half_t* phiT   = thetaT + (size_t)BATCH * LEN * CI;          //  8.4 MB
    half_t* gH     = phiT   + (size_t)BATCH * KLEN * CI;         //  8.4 MB
    half_t* yhT    = gH     + (size_t)BATCH * CI * KLEN;         // 16.8 MB
    half_t* Wh     = yhT    + (size_t)BATCH * LEN * CI;          // 768 KB
    half_t* wzh    = Wh     + (size_t)768 * 512;                 // 256 KB
    float*  bns    = (float*)(wzh + (size_t)512 * 256);
    float*  bnq    = bns + CIN;

    hipMemsetAsync(bns, 0, 2 * CIN * sizeof(float), stream);

    wconv_kernel<<<256, 256, 0, stream>>>(tw, pw, gw, wzw, Wh, wzh);

    xpose_kernel<<<dim3(LEN / 64, CIN / 64, BATCH), 256, 0, stream>>>(x, xhT);

    projmm_kernel<<<dim3(LEN / 128, 6, BATCH), 256, 0, stream>>>(
        xhT, Wh, tb, pb, gb, thetaT, phiT, gH);

    attn_kernel<<<dim3(BATCH, LEN / 64), 256, 0, stream>>>(
        thetaT, phiT, gH, yhT);

    zmm_kernel<<<dim3(LEN / 128, CIN / 128, BATCH), 256, 0, stream>>>(
        yhT, wzh, wzb, out, bns, bnq);

    bn_kernel<<<(BATCH * CIN * LEN) / 4 / 256, 256, 0, stream>>>(
        out, x, bns, bnq, gamma, beta);
}